// Round 2
// baseline (667.742 us; speedup 1.0000x reference)
//
#include <hip/hip_runtime.h>

#define S_LEN 2048
#define HDIM  512
#define KSZ   64
#define S_T   128     // seq rows per block
#define PH    16      // rows per phase
// 1/sqrt(2048)
#define INV_SQRT_S 0.02209708691207961f

// Double-buffered h staging only. No partials, no stats: LN is one barrier +
// a pure-shuffle wave reduction. 64 KB -> still 2 blocks/CU (128 KB < 160 KB).
struct Smem {
    float lh[2][PH][HDIM];
};

__device__ __forceinline__ void lds_barrier() {
    // LDS-only barrier: drain lgkmcnt but leave global loads/stores (vmcnt) in flight.
    asm volatile("s_waitcnt lgkmcnt(0)\n\ts_barrier" ::: "memory");
}

// Proven round-0 conv structure: wr[64]+xw[64] resident, static ring indices.
// hv[] is gone (LN reads from LDS) and xp is 8-deep (8-row slack ~1100 cy
// covers HBM latency; 4 waves/SIMD TLP on top) -> live set BELOW round 0's.
template <int OFF, int BUF>
__device__ __forceinline__ void conv_phase(const float* __restrict__ xb, int sbase, int h,
                                           const float (&wr)[KSZ], float (&xw)[KSZ],
                                           float (&xp)[8], Smem* sm)
{
#pragma unroll
    for (int j = 0; j < PH; ++j) {
        const float xcur = xp[j & 7];
        // refill this slot with the row consumed 8 rows from now
        xp[j & 7] = xb[((sbase + j + 8) & (S_LEN - 1)) * HDIM + h];

        float y0 = 0.f, y1 = 0.f, y2 = 0.f, y3 = 0.f;
#pragma unroll
        for (int k = 1; k <= KSZ - 7; k += 4) {   // k = 1,5,...,57  covers taps 1..60
            y0 = fmaf(wr[k],     xw[(OFF + j - k)     & 63], y0);
            y1 = fmaf(wr[k + 1], xw[(OFF + j - k - 1) & 63], y1);
            y2 = fmaf(wr[k + 2], xw[(OFF + j - k - 2) & 63], y2);
            y3 = fmaf(wr[k + 3], xw[(OFF + j - k - 3) & 63], y3);
        }
        y0 = fmaf(wr[61], xw[(OFF + j - 61) & 63], y0);
        y1 = fmaf(wr[62], xw[(OFF + j - 62) & 63], y1);
        y2 = fmaf(wr[63], xw[(OFF + j - 63) & 63], y2);

        const float hval = fmaf(INV_SQRT_S, fmaf(wr[0], xcur, (y0 + y1) + (y2 + y3)), xcur);
        xw[(OFF + j) & 63] = xcur;   // insert current row, retire x[s-64]
        sm->lh[BUF][j][h] = hval;    // stage for LN
    }
}

// Wave-mapped LN: wave w owns rows 2w, 2w+1. One barrier, then each wave
// loads its row once (8 regs/lane, 2-way-free LDS pattern), shuffle-reduces,
// normalizes from the SAME regs and stores. No stage-2, no stats broadcast,
// no second barrier: conv(p+1) targets the other lh buffer.
template <int BUF>
__device__ __forceinline__ void ln_phase(int sbase, int lane, int wv,
                                         const float* __restrict__ gamma,
                                         const float* __restrict__ beta,
                                         float* __restrict__ ob, Smem* sm)
{
    lds_barrier();   // all lh[BUF] writes visible; vmcnt stays in flight

    // per-lane channel coeffs; 2 KB tables are L1-resident -> cheap reload
    // each phase keeps them out of the conv live range.
    float gm[8], bt[8];
#pragma unroll
    for (int m = 0; m < 8; ++m) {
        gm[m] = gamma[lane + 64 * m];
        bt[m] = beta [lane + 64 * m];
    }

#pragma unroll
    for (int rr = 0; rr < 2; ++rr) {
        const int row = wv * 2 + rr;
        float v[8];
        float s = 0.f, q = 0.f;
#pragma unroll
        for (int m = 0; m < 8; ++m) {
            v[m] = sm->lh[BUF][row][lane + 64 * m];   // lanes 0..63 -> banks 0..31 2-way (free)
            s += v[m];
            q = fmaf(v[m], v[m], q);
        }
#pragma unroll
        for (int d = 1; d < 64; d <<= 1) {
            s += __shfl_xor(s, d, 64);
            q += __shfl_xor(q, d, 64);
        }
        const float mean = s * (1.0f / 512.0f);
        const float rstd = rsqrtf(fmaf(q, 1.0f / 512.0f, -mean * mean) + 1e-12f);

        float* op = ob + (size_t)(sbase + row) * HDIM + lane;
#pragma unroll
        for (int m = 0; m < 8; ++m)
            op[64 * m] = fmaf(v[m] - mean, rstd * gm[m], bt[m]);   // coalesced 256B bursts
    }
}

// (512,4): 4 waves/EU * 4 EU / 8 waves-per-block = 2 blocks/CU, pins VGPR<=128.
__global__ __launch_bounds__(512, 4)
void fconv_ln(const float* __restrict__ x, const float* __restrict__ w,
              const float* __restrict__ gamma, const float* __restrict__ beta,
              float* __restrict__ out)
{
    __shared__ Smem sm;
    const int h    = threadIdx.x;        // channel
    const int lane = h & 63;
    const int wv   = h >> 6;
    const int b  = blockIdx.x >> 4;      // 16 tiles of 128 rows per batch
    const int s0 = (blockIdx.x & 15) * S_T;

    const float* xb = x   + (size_t)b * S_LEN * HDIM;
    float*       ob = out + (size_t)b * S_LEN * HDIM;

    float wr[KSZ];
#pragma unroll
    for (int k = 0; k < KSZ; ++k) wr[k] = w[k * HDIM + h];

    // window init: slot (s - s0) & 63 holds x[s] for s in [s0-63, s0-1]
    float xw[KSZ];
#pragma unroll
    for (int d = 1; d < KSZ; ++d)
        xw[KSZ - d] = xb[((s0 - d) & (S_LEN - 1)) * HDIM + h];
    xw[0] = 0.f;

    // prefetch pipeline: rows s0 .. s0+7
    float xp[8];
#pragma unroll
    for (int j = 0; j < 8; ++j) xp[j] = xb[(s0 + j) * HDIM + h];

    for (int grp = 0; grp < S_T / 64; ++grp) {   // 2 iterations
        const int base = s0 + grp * 64;
        conv_phase< 0, 0>(xb, base +  0, h, wr, xw, xp, &sm); ln_phase<0>(base +  0, lane, wv, gamma, beta, ob, &sm);
        conv_phase<16, 1>(xb, base + 16, h, wr, xw, xp, &sm); ln_phase<1>(base + 16, lane, wv, gamma, beta, ob, &sm);
        conv_phase<32, 0>(xb, base + 32, h, wr, xw, xp, &sm); ln_phase<0>(base + 32, lane, wv, gamma, beta, ob, &sm);
        conv_phase<48, 1>(xb, base + 48, h, wr, xw, xp, &sm); ln_phase<1>(base + 48, lane, wv, gamma, beta, ob, &sm);
    }
}

extern "C" void kernel_launch(void* const* d_in, const int* in_sizes, int n_in,
                              void* d_out, int out_size, void* d_ws, size_t ws_size,
                              hipStream_t stream) {
    const float* x  = (const float*)d_in[0];   // [32, 2048, 512] fp32
    const float* w  = (const float*)d_in[1];   // [1, 64, 512]   fp32
    const float* g  = (const float*)d_in[2];   // [512]
    const float* b  = (const float*)d_in[3];   // [512]
    float* o        = (float*)d_out;           // [32, 2048, 512] fp32

    (void)in_sizes; (void)n_in; (void)out_size; (void)d_ws; (void)ws_size;
    fconv_ln<<<dim3(32 * (S_LEN / S_T)), dim3(HDIM), 0, stream>>>(x, w, g, b, o);
}

// Round 3
// 275.127 us; speedup vs baseline: 2.4270x; 2.4270x over previous
//
#include <hip/hip_runtime.h>

#define S_LEN 2048
#define HDIM  512
#define KSZ   64
#define S_T   128     // seq rows per block
#define PH    16      // rows per phase
// 1/sqrt(2048)
#define INV_SQRT_S 0.02209708691207961f

// Double-buffered h staging only. No partials, no stats: LN is one barrier +
// a pure-shuffle wave reduction. 64 KB -> still 2 blocks/CU (128 KB < 160 KB).
struct Smem {
    float lh[2][PH][HDIM];
};

__device__ __forceinline__ void lds_barrier() {
    // LDS-only barrier: drain lgkmcnt but leave global loads/stores (vmcnt) in flight.
    asm volatile("s_waitcnt lgkmcnt(0)\n\ts_barrier" ::: "memory");
}

// Round-0-proven conv structure: wr[64]+xw[64] resident, static ring indices.
template <int OFF, int BUF>
__device__ __forceinline__ void conv_phase(const float* __restrict__ xb, int sbase, int h,
                                           const float (&wr)[KSZ], float (&xw)[KSZ],
                                           float (&xp)[8], Smem* sm)
{
#pragma unroll
    for (int j = 0; j < PH; ++j) {
        const float xcur = xp[j & 7];
        // refill this slot with the row consumed 8 rows from now
        xp[j & 7] = xb[((sbase + j + 8) & (S_LEN - 1)) * HDIM + h];

        float y0 = 0.f, y1 = 0.f, y2 = 0.f, y3 = 0.f;
#pragma unroll
        for (int k = 1; k <= KSZ - 7; k += 4) {   // k = 1,5,...,57  covers taps 1..60
            y0 = fmaf(wr[k],     xw[(OFF + j - k)     & 63], y0);
            y1 = fmaf(wr[k + 1], xw[(OFF + j - k - 1) & 63], y1);
            y2 = fmaf(wr[k + 2], xw[(OFF + j - k - 2) & 63], y2);
            y3 = fmaf(wr[k + 3], xw[(OFF + j - k - 3) & 63], y3);
        }
        y0 = fmaf(wr[61], xw[(OFF + j - 61) & 63], y0);
        y1 = fmaf(wr[62], xw[(OFF + j - 62) & 63], y1);
        y2 = fmaf(wr[63], xw[(OFF + j - 63) & 63], y2);

        const float hval = fmaf(INV_SQRT_S, fmaf(wr[0], xcur, (y0 + y1) + (y2 + y3)), xcur);
        xw[(OFF + j) & 63] = xcur;   // insert current row, retire x[s-64]
        sm->lh[BUF][j][h] = hval;    // stage for LN
    }
}

// Wave-mapped LN: wave w owns rows 2w, 2w+1. One barrier, then each wave
// loads its row once (8 regs/lane, 2-way-free LDS pattern -> 0 conflicts,
// verified round 2), shuffle-reduces, normalizes from the SAME regs and
// stores. No stage-2, no stats broadcast, no second barrier: conv(p+1)
// targets the other lh buffer.
template <int BUF>
__device__ __forceinline__ void ln_phase(int sbase, int lane, int wv,
                                         const float* __restrict__ gamma,
                                         const float* __restrict__ beta,
                                         float* __restrict__ ob, Smem* sm)
{
    lds_barrier();   // all lh[BUF] writes visible; vmcnt stays in flight

    // per-lane channel coeffs; 2 KB tables are L1-resident -> cheap reload
    // each phase keeps them out of the conv live range.
    float gm[8], bt[8];
#pragma unroll
    for (int m = 0; m < 8; ++m) {
        gm[m] = gamma[lane + 64 * m];
        bt[m] = beta [lane + 64 * m];
    }

#pragma unroll
    for (int rr = 0; rr < 2; ++rr) {
        const int row = wv * 2 + rr;
        float v[8];
        float s = 0.f, q = 0.f;
#pragma unroll
        for (int m = 0; m < 8; ++m) {
            v[m] = sm->lh[BUF][row][lane + 64 * m];   // 2 lanes/bank: conflict-free
            s += v[m];
            q = fmaf(v[m], v[m], q);
        }
#pragma unroll
        for (int d = 1; d < 64; d <<= 1) {
            s += __shfl_xor(s, d, 64);
            q += __shfl_xor(q, d, 64);
        }
        const float mean = s * (1.0f / 512.0f);
        const float rstd = rsqrtf(fmaf(q, 1.0f / 512.0f, -mean * mean) + 1e-12f);

        float* op = ob + (size_t)(sbase + row) * HDIM + lane;
#pragma unroll
        for (int m = 0; m < 8; ++m)
            op[64 * m] = fmaf(v[m] - mean, rstd * gm[m], bt[m]);   // coalesced 256B bursts
    }
}

// (512,2): on THIS toolchain the 2nd arg acts like min-blocks-per-CU
// (empirical: (512,2)->128 VGPR cap rounds 0-1, (512,4)->64 VGPR + massive
// spill round 2). 2 blocks/CU = 16 waves/CU, VGPR capped at 128.
__global__ __launch_bounds__(512, 2)
void fconv_ln(const float* __restrict__ x, const float* __restrict__ w,
              const float* __restrict__ gamma, const float* __restrict__ beta,
              float* __restrict__ out)
{
    __shared__ Smem sm;
    const int h    = threadIdx.x;        // channel
    const int lane = h & 63;
    const int wv   = h >> 6;
    const int b  = blockIdx.x >> 4;      // 16 tiles of 128 rows per batch
    const int s0 = (blockIdx.x & 15) * S_T;

    const float* xb = x   + (size_t)b * S_LEN * HDIM;
    float*       ob = out + (size_t)b * S_LEN * HDIM;

    float wr[KSZ];
#pragma unroll
    for (int k = 0; k < KSZ; ++k) wr[k] = w[k * HDIM + h];

    // window init: slot (s - s0) & 63 holds x[s] for s in [s0-63, s0-1]
    float xw[KSZ];
#pragma unroll
    for (int d = 1; d < KSZ; ++d)
        xw[KSZ - d] = xb[((s0 - d) & (S_LEN - 1)) * HDIM + h];
    xw[0] = 0.f;

    // prefetch pipeline: rows s0 .. s0+7
    float xp[8];
#pragma unroll
    for (int j = 0; j < 8; ++j) xp[j] = xb[(s0 + j) * HDIM + h];

    for (int grp = 0; grp < S_T / 64; ++grp) {   // 2 iterations
        const int base = s0 + grp * 64;
        conv_phase< 0, 0>(xb, base +  0, h, wr, xw, xp, &sm); ln_phase<0>(base +  0, lane, wv, gamma, beta, ob, &sm);
        conv_phase<16, 1>(xb, base + 16, h, wr, xw, xp, &sm); ln_phase<1>(base + 16, lane, wv, gamma, beta, ob, &sm);
        conv_phase<32, 0>(xb, base + 32, h, wr, xw, xp, &sm); ln_phase<0>(base + 32, lane, wv, gamma, beta, ob, &sm);
        conv_phase<48, 1>(xb, base + 48, h, wr, xw, xp, &sm); ln_phase<1>(base + 48, lane, wv, gamma, beta, ob, &sm);
    }
}

extern "C" void kernel_launch(void* const* d_in, const int* in_sizes, int n_in,
                              void* d_out, int out_size, void* d_ws, size_t ws_size,
                              hipStream_t stream) {
    const float* x  = (const float*)d_in[0];   // [32, 2048, 512] fp32
    const float* w  = (const float*)d_in[1];   // [1, 64, 512]   fp32
    const float* g  = (const float*)d_in[2];   // [512]
    const float* b  = (const float*)d_in[3];   // [512]
    float* o        = (float*)d_out;           // [32, 2048, 512] fp32

    (void)in_sizes; (void)n_in; (void)out_size; (void)d_ws; (void)ws_size;
    fconv_ln<<<dim3(32 * (S_LEN / S_T)), dim3(HDIM), 0, stream>>>(x, w, g, b, o);
}